// Round 11
// baseline (490.233 us; speedup 1.0000x reference)
//
#include <hip/hip_runtime.h>
#include <hip/hip_bf16.h>

typedef __attribute__((ext_vector_type(8))) short bf16x8;
typedef __attribute__((ext_vector_type(4))) float f32x4;

#define NB   256
#define TT   512
#define DDEC 512
#define DENC 1024
#define DATT 128
#define NF   32
#define KW   31
#define PW   15

// global -> LDS direct DMA, 16B/lane; dest = wave-uniform base + lane*16.
#define GLDS16(g, l)                                                        \
  __builtin_amdgcn_global_load_lds(                                         \
      (const __attribute__((address_space(1))) void*)(uintptr_t)(g),        \
      (__attribute__((address_space(3))) void*)(uintptr_t)(l), 16, 0, 0)

__device__ __forceinline__ float fast_tanh(float x) {
  float e = __expf(2.f * x);
  return 1.f - 2.f / (e + 1.f);
}

// ---------- prep: WkT[a][k] = bf16(Wk[k][a]) ----------
__global__ __launch_bounds__(256) void prep_wkt(const float* __restrict__ Wk,
                                                __hip_bfloat16* __restrict__ WkT) {
  int idx = blockIdx.x * 256 + threadIdx.x;
  int k2 = idx >> 7, a = idx & 127;
  int k = k2 * 2;
  union { ushort2 u; __hip_bfloat16 h[2]; } cv;
  cv.h[0] = __float2bfloat16(Wk[(size_t)k * DATT + a]);
  cv.h[1] = __float2bfloat16(Wk[(size_t)(k + 1) * DATT + a]);
  *reinterpret_cast<ushort2*>(WkT + (size_t)a * 1024 + k) = cv.u;
}

// ---------- prep: wlocT[a][f] = bf16(Wloc[f][a]) ----------
__global__ __launch_bounds__(256) void prep_wloc(const float* __restrict__ Wloc,
                                                 __hip_bfloat16* __restrict__ wlocT) {
  int idx = blockIdx.x * 256 + threadIdx.x;   // 4096 = (a,f)
  int a = idx >> 5, f = idx & 31;
  wlocT[idx] = __float2bfloat16(Wloc[(size_t)f * DATT + a]);
}

// ---------- prep: qv[b][a] = query[b,:] @ Wq[:,a] ----------
__global__ __launch_bounds__(128) void prep_qv(const float* __restrict__ query,
                                               const float* __restrict__ Wq,
                                               float* __restrict__ qvg) {
  __shared__ float qr[DDEC];
  const int b = blockIdx.x, tid = threadIdx.x;
  for (int i = tid; i < DDEC; i += 128) qr[i] = query[(size_t)b * DDEC + i];
  __syncthreads();
  float a0 = 0.f, a1 = 0.f, a2 = 0.f, a3 = 0.f;
#pragma unroll 4
  for (int d = 0; d < DDEC; d += 4) {
    a0 = fmaf(qr[d + 0], Wq[(size_t)(d + 0) * DATT + tid], a0);
    a1 = fmaf(qr[d + 1], Wq[(size_t)(d + 1) * DATT + tid], a1);
    a2 = fmaf(qr[d + 2], Wq[(size_t)(d + 2) * DATT + tid], a2);
    a3 = fmaf(qr[d + 3], Wq[(size_t)(d + 3) * DATT + tid], a3);
  }
  qvg[(size_t)b * DATT + tid] = (a0 + a1) + (a2 + a3);
}

// ---------- prep: locf[b][t][f] = bf16(conv1d(attw)[f][t]) ----------
__global__ __launch_bounds__(512) void prep_locf(const float* __restrict__ attwg,
                                                 const float* __restrict__ convw,
                                                 const float* __restrict__ convb,
                                                 __hip_bfloat16* __restrict__ locf) {
  __shared__ float at[TT + 2 * PW];
  __shared__ float cw[NF][KW];
  __shared__ float cb[NF];
  const int b = blockIdx.x, t = threadIdx.x;
  for (int i = t; i < TT + 2 * PW; i += 512) {
    int g = i - PW;
    at[i] = (g >= 0 && g < TT) ? attwg[(size_t)b * TT + g] : 0.f;
  }
  for (int i = t; i < NF * KW; i += 512) cw[i / KW][i % KW] = convw[i];
  if (t < NF) cb[t] = convb[t];
  __syncthreads();
  union { __hip_bfloat16 h[NF]; ushort4 u4[8]; } o;
#pragma unroll
  for (int f = 0; f < NF; ++f) {
    float a = cb[f];
#pragma unroll
    for (int k = 0; k < KW; ++k) a = fmaf(cw[f][k], at[t + k], a);
    o.h[f] = __float2bfloat16(a);
  }
  ushort4* dst = reinterpret_cast<ushort4*>(locf + ((size_t)b * TT + t) * NF);
#pragma unroll
  for (int i = 0; i < 8; ++i) dst[i] = o.u4[i];
}

// ---------- energy_v3: 1KB-granule DMA + never-drain double-buffer ----------
struct E3Smem {
  float buf[2][32][260];   // 66,560 B ; row stride 1040 B (2-way bank aliasing)
  float qv[DATT];
  float wsc[DATT];
  float epart[32];
};                          // ~67.8 KB -> 2 blocks/CU

__global__ __launch_bounds__(256, 2) void energy_v3(
    const float* __restrict__ enc,
    const __hip_bfloat16* __restrict__ WkT,
    const __hip_bfloat16* __restrict__ wlocT,
    const __hip_bfloat16* __restrict__ locf,
    const float* __restrict__ qvg,
    const float* __restrict__ wscore,
    float* __restrict__ energy_ws) {
  __shared__ E3Smem sm;
  const int b = blockIdx.x >> 4, rc = blockIdx.x & 15;  // 16 rowchunks of 32
  const int tid = threadIdx.x, lane = tid & 63, wv = tid >> 6;  // 4 waves
  const int rg = wv >> 1, ch = wv & 1;   // rowgroup(16) x colhalf(64)
  const int lrow = lane & 15, lgrp = lane >> 4;
  const int R0 = rc * 32;
  const size_t growbase = (size_t)b * TT + R0;

  if (tid < DATT) sm.qv[tid] = qvg[(size_t)b * DATT + tid];
  else if (tid < 2 * DATT) sm.wsc[tid - DATT] = wscore[tid - DATT];

  // wave wv stages rows wv*8 .. wv*8+7; one GLDS16 = one contiguous 1KB row-chunk
  auto STAGE = [&](int p, int c) {
#pragma unroll
    for (int i = 0; i < 8; ++i) {
      const int r = wv * 8 + i;
      const float* src = enc + (growbase + r) * DENC + c * 256 + lane * 4;
      GLDS16(src, &sm.buf[p][r][0]);
    }
  };

  STAGE(0, 0);                      // prologue prefetch, stays in flight

  f32x4 acc[4];
#pragma unroll
  for (int n = 0; n < 4; ++n) acc[n] = (f32x4){0.f, 0.f, 0.f, 0.f};

  const __hip_bfloat16* pbase = WkT + (size_t)(ch * 64 + lrow) * 1024 + lgrp * 8;
  bf16x8 q0[4], q1[4];

#define E3_LOADB(Q, POS)                                                      \
  { _Pragma("unroll") for (int n = 0; n < 4; ++n)                             \
      Q[n] = *reinterpret_cast<const bf16x8*>(                                \
          pbase + (size_t)n * 16384 + (POS) * 32); }

#define E3_STEP(Q, CUR, S)                                                    \
  {                                                                           \
    const float* rb_ = &sm.buf[(CUR)][rg * 16 + lrow][(S) * 32 + lgrp * 8];   \
    float4 f0_ = *reinterpret_cast<const float4*>(rb_);                       \
    float4 f1_ = *reinterpret_cast<const float4*>(rb_ + 4);                   \
    union { bf16x8 v; __hip_bfloat16 h[8]; } cv_;                             \
    cv_.h[0] = __float2bfloat16(f0_.x); cv_.h[1] = __float2bfloat16(f0_.y);   \
    cv_.h[2] = __float2bfloat16(f0_.z); cv_.h[3] = __float2bfloat16(f0_.w);   \
    cv_.h[4] = __float2bfloat16(f1_.x); cv_.h[5] = __float2bfloat16(f1_.y);   \
    cv_.h[6] = __float2bfloat16(f1_.z); cv_.h[7] = __float2bfloat16(f1_.w);   \
    _Pragma("unroll") for (int n = 0; n < 4; ++n)                             \
      acc[n] = __builtin_amdgcn_mfma_f32_16x16x32_bf16(                       \
          cv_.v, Q[n], acc[n], 0, 0, 0);                                      \
  }

#pragma unroll 1
  for (int c = 0; c < 4; ++c) {
    const int cur = c & 1;
    // own stage(c) retired; all waves aligned -> tile c fully visible
    asm volatile("s_waitcnt vmcnt(0) lgkmcnt(0)" ::: "memory");
    __builtin_amdgcn_sched_barrier(0);
    __builtin_amdgcn_s_barrier();
    __builtin_amdgcn_sched_barrier(0);
    if (c < 3) STAGE(cur ^ 1, c + 1);   // in flight through whole chunk compute
    __builtin_amdgcn_sched_barrier(0);
    const int k0 = c * 8;
    E3_LOADB(q0, k0 + 0);
    E3_LOADB(q1, k0 + 1);
    E3_STEP(q0, cur, 0);  E3_LOADB(q0, k0 + 2);
    E3_STEP(q1, cur, 1);  E3_LOADB(q1, k0 + 3);
    E3_STEP(q0, cur, 2);  E3_LOADB(q0, k0 + 4);
    E3_STEP(q1, cur, 3);  E3_LOADB(q1, k0 + 5);
    E3_STEP(q0, cur, 4);  E3_LOADB(q0, k0 + 6);
    E3_STEP(q1, cur, 5);  E3_LOADB(q1, k0 + 7);
    E3_STEP(q0, cur, 6);
    E3_STEP(q1, cur, 7);
  }
#undef E3_LOADB
#undef E3_STEP

  // loc MFMA (K=32 of location features, L2-hot)
  {
    bf16x8 alA = *reinterpret_cast<const bf16x8*>(
        locf + (growbase + rg * 16 + lrow) * NF + lgrp * 8);
#pragma unroll
    for (int n = 0; n < 4; ++n) {
      bf16x8 blB = *reinterpret_cast<const bf16x8*>(
          wlocT + (size_t)(ch * 64 + n * 16 + lrow) * NF + lgrp * 8);
      acc[n] = __builtin_amdgcn_mfma_f32_16x16x32_bf16(alA, blB, acc[n], 0, 0, 0);
    }
  }

  // epilogue: e[row] partial over this colhalf; combine across ch via LDS
  float evals[4];
#pragma unroll
  for (int r = 0; r < 4; ++r) {
    float e = 0.f;
#pragma unroll
    for (int n = 0; n < 4; ++n) {
      const int col = ch * 64 + n * 16 + lrow;
      float v = acc[n][r] + sm.qv[col];
      e = fmaf(fast_tanh(v), sm.wsc[col], e);
    }
    e += __shfl_xor(e, 1);
    e += __shfl_xor(e, 2);
    e += __shfl_xor(e, 4);
    e += __shfl_xor(e, 8);
    evals[r] = e;
    if (ch == 0 && lrow == 0) sm.epart[rg * 16 + lgrp * 4 + r] = e;
  }
  __syncthreads();
  if (ch == 1 && lrow == 0) {
#pragma unroll
    for (int r = 0; r < 4; ++r) {
      const int row = rg * 16 + lgrp * 4 + r;
      energy_ws[(size_t)b * TT + R0 + row] = evals[r] + sm.epart[row];
    }
  }
}

// ---------- softmax over T ----------
__global__ __launch_bounds__(512) void softmax_kernel(
    const float* __restrict__ energy_ws, float* __restrict__ out_w) {
  __shared__ float red[8];
  __shared__ float scal[2];
  const int b = blockIdx.x, tid = threadIdx.x;
  const int lane = tid & 63, wv = tid >> 6;
  const float e0 = energy_ws[(size_t)b * TT + tid];
  float m1 = e0;
#pragma unroll
  for (int off = 1; off < 64; off <<= 1) m1 = fmaxf(m1, __shfl_xor(m1, off));
  if (lane == 0) red[wv] = m1;
  __syncthreads();
  if (tid == 0) {
    float mm = red[0];
#pragma unroll
    for (int i = 1; i < 8; ++i) mm = fmaxf(mm, red[i]);
    scal[0] = mm;
  }
  __syncthreads();
  const float ex = __expf(e0 - scal[0]);
  float s1 = ex;
#pragma unroll
  for (int off = 1; off < 64; off <<= 1) s1 += __shfl_xor(s1, off);
  if (lane == 0) red[wv] = s1;
  __syncthreads();
  if (tid == 0) {
    float ss = 0.f;
#pragma unroll
    for (int i = 0; i < 8; ++i) ss += red[i];
    scal[1] = 1.f / ss;
  }
  __syncthreads();
  out_w[(size_t)b * TT + tid] = ex * scal[1];
}

// ---------- ctx partials: 128 rows/block, contiguous float4 stream ----------
__global__ __launch_bounds__(256) void ctx_partial_kernel(
    const float* __restrict__ enc, const float* __restrict__ w,
    float* __restrict__ ctxp) {
  __shared__ float ws[128];
  const int b = blockIdx.x >> 2, q = blockIdx.x & 3;
  const int tid = threadIdx.x;
  if (tid < 128) ws[tid] = w[(size_t)b * TT + q * 128 + tid];
  __syncthreads();
  const float* base = enc + ((size_t)b * TT + q * 128) * DENC + tid * 4;
  float4 a = {0.f, 0.f, 0.f, 0.f};
#pragma unroll 8
  for (int r = 0; r < 128; ++r) {
    float4 v = *reinterpret_cast<const float4*>(base + (size_t)r * DENC);
    const float wt = ws[r];
    a.x = fmaf(wt, v.x, a.x);
    a.y = fmaf(wt, v.y, a.y);
    a.z = fmaf(wt, v.z, a.z);
    a.w = fmaf(wt, v.w, a.w);
  }
  *reinterpret_cast<float4*>(ctxp + ((size_t)(b * 4 + q)) * DENC + tid * 4) = a;
}

// ---------- reduce partials + context @ Wv ----------
__global__ __launch_bounds__(512) void ctx_proj_kernel(
    const float* __restrict__ ctxp, const float* __restrict__ Wv,
    float* __restrict__ out) {
  __shared__ float sc[DENC];
  const int b = blockIdx.x, tid = threadIdx.x;
  for (int i = tid; i < DENC; i += 512) {
    float s = 0.f;
#pragma unroll
    for (int qq = 0; qq < 4; ++qq) s += ctxp[((size_t)(b * 4 + qq)) * DENC + i];
    sc[i] = s;
  }
  __syncthreads();
  float acc = 0.f;
#pragma unroll 8
  for (int dd = 0; dd < DENC; ++dd)
    acc = fmaf(sc[dd], Wv[(size_t)dd * DDEC + tid], acc);
  out[(size_t)b * DDEC + tid] = acc;
}

extern "C" void kernel_launch(void* const* d_in, const int* in_sizes, int n_in,
                              void* d_out, int out_size, void* d_ws, size_t ws_size,
                              hipStream_t stream) {
  const float* query  = (const float*)d_in[0];
  const float* enc    = (const float*)d_in[1];
  const float* attw   = (const float*)d_in[2];
  const float* Wq     = (const float*)d_in[3];
  const float* Wk     = (const float*)d_in[4];
  const float* Wv     = (const float*)d_in[5];
  const float* Wloc   = (const float*)d_in[6];
  const float* convw  = (const float*)d_in[7];
  const float* convb  = (const float*)d_in[8];
  const float* wscore = (const float*)d_in[9];

  float* ctx  = (float*)d_out;               // [256][512]
  float* neww = (float*)d_out + NB * TT;     // [256][512]

  char* ws = (char*)d_ws;
  float* ctxp            = (float*)ws;                       // 4 MB
  __hip_bfloat16* WkT    = (__hip_bfloat16*)(ws + 4194304);  // 256 KB
  float* qvg             = (float*)(ws + 4456448);           // 128 KB
  float* energy_ws       = (float*)(ws + 4587520);           // 512 KB
  __hip_bfloat16* wlocT  = (__hip_bfloat16*)(ws + 5111808);  // 8 KB
  __hip_bfloat16* locf   = (__hip_bfloat16*)(ws + 5120000);  // 8 MB

  hipLaunchKernelGGL(prep_wkt, dim3(256), dim3(256), 0, stream, Wk, WkT);
  hipLaunchKernelGGL(prep_wloc, dim3(16), dim3(256), 0, stream, Wloc, wlocT);
  hipLaunchKernelGGL(prep_qv, dim3(NB), dim3(128), 0, stream, query, Wq, qvg);
  hipLaunchKernelGGL(prep_locf, dim3(NB), dim3(512), 0, stream,
                     attw, convw, convb, locf);
  hipLaunchKernelGGL(energy_v3, dim3(NB * 16), dim3(256), 0, stream,
                     enc, WkT, wlocT, locf, qvg, wscore, energy_ws);
  hipLaunchKernelGGL(softmax_kernel, dim3(NB), dim3(512), 0, stream,
                     energy_ws, neww);
  hipLaunchKernelGGL(ctx_partial_kernel, dim3(NB * 4), dim3(256), 0, stream,
                     enc, neww, ctxp);
  hipLaunchKernelGGL(ctx_proj_kernel, dim3(NB), dim3(512), 0, stream,
                     ctxp, Wv, ctx);
}

// Round 12
// 358.322 us; speedup vs baseline: 1.3681x; 1.3681x over previous
//
#include <hip/hip_runtime.h>
#include <hip/hip_bf16.h>

typedef __attribute__((ext_vector_type(8))) short bf16x8;
typedef __attribute__((ext_vector_type(4))) float f32x4;

#define NB   256
#define TT   512
#define DDEC 512
#define DENC 1024
#define DATT 128
#define NF   32
#define KW   31
#define PW   15

__device__ __forceinline__ float fast_tanh(float x) {
  float e = __expf(2.f * x);
  return 1.f - 2.f / (e + 1.f);
}

// ---------- prep: WkT[a][k] = bf16(Wk[k][a]) ----------
__global__ __launch_bounds__(256) void prep_wkt(const float* __restrict__ Wk,
                                                __hip_bfloat16* __restrict__ WkT) {
  int idx = blockIdx.x * 256 + threadIdx.x;
  int k2 = idx >> 7, a = idx & 127;
  int k = k2 * 2;
  union { ushort2 u; __hip_bfloat16 h[2]; } cv;
  cv.h[0] = __float2bfloat16(Wk[(size_t)k * DATT + a]);
  cv.h[1] = __float2bfloat16(Wk[(size_t)(k + 1) * DATT + a]);
  *reinterpret_cast<ushort2*>(WkT + (size_t)a * 1024 + k) = cv.u;
}

// ---------- prep: wlocT[a][f] = bf16(Wloc[f][a]) ----------
__global__ __launch_bounds__(256) void prep_wloc(const float* __restrict__ Wloc,
                                                 __hip_bfloat16* __restrict__ wlocT) {
  int idx = blockIdx.x * 256 + threadIdx.x;   // 4096 = (a,f)
  int a = idx >> 5, f = idx & 31;
  wlocT[idx] = __float2bfloat16(Wloc[(size_t)f * DATT + a]);
}

// ---------- prep: qv[b][a] = query[b,:] @ Wq[:,a] ----------
__global__ __launch_bounds__(128) void prep_qv(const float* __restrict__ query,
                                               const float* __restrict__ Wq,
                                               float* __restrict__ qvg) {
  __shared__ float qr[DDEC];
  const int b = blockIdx.x, tid = threadIdx.x;
  for (int i = tid; i < DDEC; i += 128) qr[i] = query[(size_t)b * DDEC + i];
  __syncthreads();
  float a0 = 0.f, a1 = 0.f, a2 = 0.f, a3 = 0.f;
#pragma unroll 4
  for (int d = 0; d < DDEC; d += 4) {
    a0 = fmaf(qr[d + 0], Wq[(size_t)(d + 0) * DATT + tid], a0);
    a1 = fmaf(qr[d + 1], Wq[(size_t)(d + 1) * DATT + tid], a1);
    a2 = fmaf(qr[d + 2], Wq[(size_t)(d + 2) * DATT + tid], a2);
    a3 = fmaf(qr[d + 3], Wq[(size_t)(d + 3) * DATT + tid], a3);
  }
  qvg[(size_t)b * DATT + tid] = (a0 + a1) + (a2 + a3);
}

// ---------- prep: locf[b][t][f] = bf16(conv1d(attw)[f][t]) ----------
__global__ __launch_bounds__(512) void prep_locf(const float* __restrict__ attwg,
                                                 const float* __restrict__ convw,
                                                 const float* __restrict__ convb,
                                                 __hip_bfloat16* __restrict__ locf) {
  __shared__ float at[TT + 2 * PW];
  __shared__ float cw[NF][KW];
  __shared__ float cb[NF];
  const int b = blockIdx.x, t = threadIdx.x;
  for (int i = t; i < TT + 2 * PW; i += 512) {
    int g = i - PW;
    at[i] = (g >= 0 && g < TT) ? attwg[(size_t)b * TT + g] : 0.f;
  }
  for (int i = t; i < NF * KW; i += 512) cw[i / KW][i % KW] = convw[i];
  if (t < NF) cb[t] = convb[t];
  __syncthreads();
  union { __hip_bfloat16 h[NF]; ushort4 u4[8]; } o;
#pragma unroll
  for (int f = 0; f < NF; ++f) {
    float a = cb[f];
#pragma unroll
    for (int k = 0; k < KW; ++k) a = fmaf(cw[f][k], at[t + k], a);
    o.h[f] = __float2bfloat16(a);
  }
  ushort4* dst = reinterpret_cast<ushort4*>(locf + ((size_t)b * TT + t) * NF);
#pragma unroll
  for (int i = 0; i < 8; ++i) dst[i] = o.u4[i];
}

// ---------- epass: energy MFMA + block softmax partial + ctx partial ----------
// one block = (b, q): 128 rows. enc read from HBM once; ctx re-read is L2/L3-hot.
struct EPSmem {
  float qv[DATT];
  float wsc[DATT];
  float e_sm[128];
  float p_sm[128];
  float part[4];
  float scal[2];
};

__global__ __launch_bounds__(256, 2) void epass_kernel(
    const float* __restrict__ enc,
    const __hip_bfloat16* __restrict__ WkT,
    const __hip_bfloat16* __restrict__ wlocT,
    const __hip_bfloat16* __restrict__ locf,
    const float* __restrict__ qvg,
    const float* __restrict__ wscore,
    float* __restrict__ energy_ws,
    float* __restrict__ mblk,
    float* __restrict__ sblk,
    float* __restrict__ ctxp) {
  __shared__ EPSmem sm;
  const int b = blockIdx.x >> 2, q = blockIdx.x & 3;    // 4 chunks of 128 rows
  const int tid = threadIdx.x, lane = tid & 63, wv = tid >> 6;  // 4 waves x 32 rows
  const int lrow = lane & 15, lgrp = lane >> 4;
  const size_t growbase = (size_t)b * TT + q * 128;

  if (tid < DATT) sm.qv[tid] = qvg[(size_t)b * DATT + tid];
  else sm.wsc[tid - DATT] = wscore[tid - DATT];
  __syncthreads();

  const float* pa = enc + (growbase + wv * 32 + lrow) * DENC + lgrp * 8;
  const __hip_bfloat16* pb = WkT + (size_t)lrow * 1024 + lgrp * 8;

  float4 aqA[4], aqB[4];
  bf16x8 bb[8];
  f32x4 acc[2][8];
#pragma unroll
  for (int m = 0; m < 2; ++m)
#pragma unroll
    for (int n = 0; n < 8; ++n) acc[m][n] = (f32x4){0.f, 0.f, 0.f, 0.f};

#define ELOADA(Q, S)                                                          \
  {                                                                           \
    _Pragma("unroll") for (int m = 0; m < 2; ++m) {                           \
      const float* p_ = pa + (size_t)m * 16 * DENC + (S) * 32;                \
      Q[2 * m]     = *reinterpret_cast<const float4*>(p_);                    \
      Q[2 * m + 1] = *reinterpret_cast<const float4*>(p_ + 4);                \
    }                                                                         \
  }
#define ELOADB(S)                                                             \
  {                                                                           \
    _Pragma("unroll") for (int n = 0; n < 8; ++n)                             \
      bb[n] = *reinterpret_cast<const bf16x8*>(                               \
          pb + (size_t)n * 16 * 1024 + (S) * 32);                             \
  }
#define ESTEP(Q)                                                              \
  {                                                                           \
    _Pragma("unroll") for (int m = 0; m < 2; ++m) {                           \
      union { bf16x8 v; __hip_bfloat16 h[8]; } cv_;                           \
      cv_.h[0] = __float2bfloat16(Q[2 * m].x);                                \
      cv_.h[1] = __float2bfloat16(Q[2 * m].y);                                \
      cv_.h[2] = __float2bfloat16(Q[2 * m].z);                                \
      cv_.h[3] = __float2bfloat16(Q[2 * m].w);                                \
      cv_.h[4] = __float2bfloat16(Q[2 * m + 1].x);                            \
      cv_.h[5] = __float2bfloat16(Q[2 * m + 1].y);                            \
      cv_.h[6] = __float2bfloat16(Q[2 * m + 1].z);                            \
      cv_.h[7] = __float2bfloat16(Q[2 * m + 1].w);                            \
      _Pragma("unroll") for (int n = 0; n < 8; ++n)                           \
        acc[m][n] = __builtin_amdgcn_mfma_f32_16x16x32_bf16(                  \
            cv_.v, bb[n], acc[m][n], 0, 0, 0);                                \
    }                                                                         \
  }

  ELOADA(aqA, 0);
#pragma unroll 1
  for (int s = 0; s < 32; s += 2) {
    ELOADB(s);
    ELOADA(aqB, s + 1);
    ESTEP(aqA);
    ELOADB(s + 1);
    if (s + 2 < 32) ELOADA(aqA, s + 2);
    ESTEP(aqB);
  }
#undef ELOADA
#undef ELOADB
#undef ESTEP

  // loc MFMA (K=32 of location features; L2-hot)
  {
    bf16x8 alA[2];
    const __hip_bfloat16* pl =
        locf + (growbase + wv * 32 + lrow) * NF + lgrp * 8;
#pragma unroll
    for (int m = 0; m < 2; ++m)
      alA[m] = *reinterpret_cast<const bf16x8*>(pl + (size_t)m * 16 * NF);
#pragma unroll
    for (int n = 0; n < 8; ++n) {
      bf16x8 blB = *reinterpret_cast<const bf16x8*>(
          wlocT + (size_t)(n * 16 + lrow) * NF + lgrp * 8);
#pragma unroll
      for (int m = 0; m < 2; ++m)
        acc[m][n] = __builtin_amdgcn_mfma_f32_16x16x32_bf16(
            alA[m], blB, acc[m][n], 0, 0, 0);
    }
  }

  // epilogue: e[row] = sum_a tanh(D + qv[a]) * wsc[a] -> e_sm
#pragma unroll
  for (int m = 0; m < 2; ++m) {
#pragma unroll
    for (int r = 0; r < 4; ++r) {
      float e = 0.f;
#pragma unroll
      for (int n = 0; n < 8; ++n) {
        const int col = n * 16 + lrow;
        float v = acc[m][n][r] + sm.qv[col];
        e = fmaf(fast_tanh(v), sm.wsc[col], e);
      }
      e += __shfl_xor(e, 1);
      e += __shfl_xor(e, 2);
      e += __shfl_xor(e, 4);
      e += __shfl_xor(e, 8);
      if (lrow == 0) sm.e_sm[wv * 32 + m * 16 + lgrp * 4 + r] = e;
    }
  }
  __syncthreads();

  // block softmax partials: m_blk, p_r, s_blk
  if (tid < 128) {
    float v = sm.e_sm[tid];
    float mx = v;
#pragma unroll
    for (int off = 1; off < 64; off <<= 1) mx = fmaxf(mx, __shfl_xor(mx, off));
    if (lane == 0) sm.part[tid >> 6] = mx;
  }
  __syncthreads();
  if (tid == 0) sm.scal[0] = fmaxf(sm.part[0], sm.part[1]);
  __syncthreads();
  const float m_blk = sm.scal[0];
  if (tid < 128) {
    float p = __expf(sm.e_sm[tid] - m_blk);
    sm.p_sm[tid] = p;
#pragma unroll
    for (int off = 1; off < 64; off <<= 1) p += __shfl_xor(p, off);
    if (lane == 0) sm.part[tid >> 6] = p;
  }
  __syncthreads();
  if (tid == 0) {
    const int blk = blockIdx.x;
    mblk[blk] = m_blk;
    sblk[blk] = sm.part[0] + sm.part[1];
  }
  if (tid < 128) energy_ws[(size_t)b * TT + q * 128 + tid] = sm.e_sm[tid];

  // ctx partial: c[d] = sum_r p_r * enc[row, d]   (tile just streamed -> L2/L3)
  const float* base = enc + growbase * DENC + tid * 4;
  float4 a = {0.f, 0.f, 0.f, 0.f};
#pragma unroll 8
  for (int r = 0; r < 128; ++r) {
    float4 v = *reinterpret_cast<const float4*>(base + (size_t)r * DENC);
    const float wt = sm.p_sm[r];
    a.x = fmaf(wt, v.x, a.x);
    a.y = fmaf(wt, v.y, a.y);
    a.z = fmaf(wt, v.z, a.z);
    a.w = fmaf(wt, v.w, a.w);
  }
  *reinterpret_cast<float4*>(ctxp + (size_t)blockIdx.x * DENC + tid * 4) = a;
}

// ---------- finalize: combine partials, emit w and ctx@Wv ----------
__global__ __launch_bounds__(512) void finalize_kernel(
    const float* __restrict__ energy_ws,
    const float* __restrict__ mblk,
    const float* __restrict__ sblk,
    const float* __restrict__ ctxp,
    const float* __restrict__ Wv,
    float* __restrict__ out_ctx,
    float* __restrict__ out_w) {
  __shared__ float sc[DENC];
  __shared__ float sc4[4];
  __shared__ float scal[2];
  const int b = blockIdx.x, tid = threadIdx.x;

  if (tid == 0) {
    float m0 = mblk[b * 4 + 0], m1 = mblk[b * 4 + 1];
    float m2 = mblk[b * 4 + 2], m3 = mblk[b * 4 + 3];
    float m = fmaxf(fmaxf(m0, m1), fmaxf(m2, m3));
    float f0 = __expf(m0 - m), f1 = __expf(m1 - m);
    float f2 = __expf(m2 - m), f3 = __expf(m3 - m);
    float S = sblk[b * 4 + 0] * f0 + sblk[b * 4 + 1] * f1 +
              sblk[b * 4 + 2] * f2 + sblk[b * 4 + 3] * f3;
    float invS = 1.f / S;
    scal[0] = m;
    scal[1] = invS;
    sc4[0] = f0 * invS; sc4[1] = f1 * invS;
    sc4[2] = f2 * invS; sc4[3] = f3 * invS;
  }
  __syncthreads();

  // attention weights
  out_w[(size_t)b * TT + tid] =
      __expf(energy_ws[(size_t)b * TT + tid] - scal[0]) * scal[1];

  // ctx_enc[d] = sum_q ctxp[q][d] * sc4[q]
#pragma unroll
  for (int h = 0; h < 2; ++h) {
    const int d = tid + h * 512;
    float s = 0.f;
#pragma unroll
    for (int qq = 0; qq < 4; ++qq)
      s += ctxp[((size_t)(b * 4 + qq)) * DENC + d] * sc4[qq];
    sc[d] = s;
  }
  __syncthreads();

  // context @ Wv
  float acc = 0.f;
#pragma unroll 8
  for (int dd = 0; dd < DENC; ++dd)
    acc = fmaf(sc[dd], Wv[(size_t)dd * DDEC + tid], acc);
  out_ctx[(size_t)b * DDEC + tid] = acc;
}

extern "C" void kernel_launch(void* const* d_in, const int* in_sizes, int n_in,
                              void* d_out, int out_size, void* d_ws, size_t ws_size,
                              hipStream_t stream) {
  const float* query  = (const float*)d_in[0];
  const float* enc    = (const float*)d_in[1];
  const float* attw   = (const float*)d_in[2];
  const float* Wq     = (const float*)d_in[3];
  const float* Wk     = (const float*)d_in[4];
  const float* Wv     = (const float*)d_in[5];
  const float* Wloc   = (const float*)d_in[6];
  const float* convw  = (const float*)d_in[7];
  const float* convb  = (const float*)d_in[8];
  const float* wscore = (const float*)d_in[9];

  float* ctx  = (float*)d_out;               // [256][512]
  float* neww = (float*)d_out + NB * TT;     // [256][512]

  char* ws = (char*)d_ws;
  float* ctxp            = (float*)ws;                       // 1024*1024*4 = 4 MB
  __hip_bfloat16* WkT    = (__hip_bfloat16*)(ws + 4194304);  // 256 KB
  float* qvg             = (float*)(ws + 4456448);           // 128 KB
  float* energy_ws       = (float*)(ws + 4587520);           // 512 KB
  __hip_bfloat16* wlocT  = (__hip_bfloat16*)(ws + 5111808);  // 8 KB
  __hip_bfloat16* locf   = (__hip_bfloat16*)(ws + 5120000);  // 8 MB
  float* mblk            = (float*)(ws + 13508608);          // 4 KB
  float* sblk            = (float*)(ws + 13512704);          // 4 KB

  hipLaunchKernelGGL(prep_wkt, dim3(256), dim3(256), 0, stream, Wk, WkT);
  hipLaunchKernelGGL(prep_wloc, dim3(16), dim3(256), 0, stream, Wloc, wlocT);
  hipLaunchKernelGGL(prep_qv, dim3(NB), dim3(128), 0, stream, query, Wq, qvg);
  hipLaunchKernelGGL(prep_locf, dim3(NB), dim3(512), 0, stream,
                     attw, convw, convb, locf);
  hipLaunchKernelGGL(epass_kernel, dim3(NB * 4), dim3(256), 0, stream,
                     enc, WkT, wlocT, locf, qvg, wscore,
                     energy_ws, mblk, sblk, ctxp);
  hipLaunchKernelGGL(finalize_kernel, dim3(NB), dim3(512), 0, stream,
                     energy_ws, mblk, sblk, ctxp, Wv, ctx, neww);
}